// Round 9
// baseline (536.309 us; speedup 1.0000x reference)
//
#include <hip/hip_runtime.h>
#include <stdint.h>

typedef unsigned short u16;
typedef __bf16 bf16x8 __attribute__((ext_vector_type(8)));
typedef float f32x4 __attribute__((ext_vector_type(4)));
typedef float f32x16 __attribute__((ext_vector_type(16)));
typedef unsigned short u16x8 __attribute__((ext_vector_type(8)));
typedef unsigned short u16x4 __attribute__((ext_vector_type(4)));

__device__ __forceinline__ float b2f(u16 b) {
    return __uint_as_float(((unsigned)b) << 16);
}
__device__ __forceinline__ u16 f2b(float f) {
    unsigned u = __float_as_uint(f);
    unsigned r = (u + 0x7fffu + ((u >> 16) & 1u)) >> 16;  // RNE
    return (u16)r;
}

#define GLDS16(g, l) __builtin_amdgcn_global_load_lds(                        \
    (const __attribute__((address_space(1))) void*)(g),                       \
    (__attribute__((address_space(3))) void*)(l), 16, 0, 0)

// ---------------------------------------------------------------------------
// 256x256-tile register-pipelined GEMM, 32x32x16 MFMA.
// C = epilogue(A @ Bt^T); A[M,K], Bt[N,K] bf16 row-major.
// 512 thr = 8 waves (2M x 4N); per-wave C = 128x64 = 4x2 blocks of 32x32.
// BK=64 as 2 K-halves stored [256 rows][4 chunks of 8] (64B rows) with
// chunk-XOR swizzle (r8, conflict-counter-verified 0):
//   physical chunk = logical chunk ^ ((row>>1)&3), applied BOTH sides.
// K-tile = 4 slices of K=16.  Per slice: 6 ds_read_b128 (4 A + 2 B),
// 8 x mfma_f32_32x32x16_bf16 (independent acc blocks).
// Reg pipeline 1 slice ahead: issue slice s+1 reads, LGK(6) drains slice s,
// MFMA slice s.  Stage halves of tile t+1 at s0..s3; CKPT(2) after s0 and
// s2 MFMAs (same outstanding-ledger as r8: each CKPT drains exactly the
// half needed one step later; every staged half flies >= 1 step).
// Fragment layouts: A/B row=lane&31, k=(lane>>5)*8+e;
// C/D col=lane&31, row=(reg&3)+8*(reg>>2)+4*(lane>>5)  [m74/m101].
// OUT_MODE: 0 = bf16 [.,N], 1 = f32 [.,N], 2 = bf16 V^T scatter
//           (b = row>>12, Vt[b][col][row&4095], batch stride 1<<22).
// ---------------------------------------------------------------------------
template<int HAS_BIAS, int RELU, int HAS_RES, int OUT_MODE>
__device__ __forceinline__ void gemm12_body(
    const u16* __restrict__ A, const u16* __restrict__ Bt,
    const float* __restrict__ bias, const float* __restrict__ res,
    void* __restrict__ Cout, int N, int K,
    long sA, long sB, long sC, long sR, float scale)
{
    __shared__ u16 smem[65536];   // 128 KiB: A [buf][half] 16KB x4, then B x4

    // chunked XCD swizzle (bijective; all grids here have nwg % 8 == 0)
    const long nwg = (long)gridDim.x * gridDim.y * gridDim.z;
    long gid = ((long)blockIdx.z * gridDim.y + blockIdx.y) * gridDim.x + blockIdx.x;
    long logical = (nwg % 8 == 0) ? (gid & 7) * (nwg >> 3) + (gid >> 3) : gid;
    const int bx = (int)(logical % gridDim.x);
    long tmp = logical / gridDim.x;
    const int by = (int)(tmp % gridDim.y);
    const int bz = (int)(tmp / gridDim.y);

    A  += (long)bz * sA;
    Bt += (long)bz * sB;

    const int tid  = threadIdx.x;
    const int lane = tid & 63, wid = tid >> 6;
    const int wm   = wid >> 2, wn = wid & 3;
    const int lr32 = lane & 31, lk2 = lane >> 5;
    const long m0  = (long)by * 256;
    const long n0  = (long)bx * 256;
    const int  NT  = K >> 6;

    // staging source with inverse chunk swizzle (identical to r8): thread tid
    // covers LDS slot (row=tid>>2, chunk=tid&3); fetches logical chunk
    // (tid&3)^((tid>>3)&3).
    const int sch = ((tid & 3) ^ ((tid >> 3) & 3)) * 8;
    const u16* gA0 = A  + (m0 + (tid >> 2)) * (long)K + sch;
    const u16* gB0 = Bt + (n0 + (tid >> 2)) * (long)K + sch;
    const u16* gA1 = gA0 + 128L * K;
    const u16* gB1 = gB0 + 128L * K;
    const int wdst = (tid & ~63) * 8;   // u16 elems

#define STA(bufn, kk, kof) do {                                               \
    GLDS16(gA0 + (kof) + (kk) * 32, &smem[(bufn)*16384 + (kk)*8192 + wdst]);  \
    GLDS16(gA1 + (kof) + (kk) * 32, &smem[(bufn)*16384 + (kk)*8192 + wdst + 4096]); } while (0)
#define STB(bufn, kk, kof) do {                                               \
    GLDS16(gB0 + (kof) + (kk) * 32, &smem[32768 + (bufn)*16384 + (kk)*8192 + wdst]); \
    GLDS16(gB1 + (kof) + (kk) * 32, &smem[32768 + (bufn)*16384 + (kk)*8192 + wdst + 4096]); } while (0)

    // fragment read bases (u16 elems): row = <block base> + lr32, 64B rows;
    // chunk = ((s&1)<<1 | lk2) ^ ((lr32>>1)&3).  cOff = base chunk offset;
    // odd slice XORs bit4 (=16 elems = chunk^2).
    const int m_   = (lr32 >> 1) & 3;
    const int cOff = ((lk2 ^ m_) << 3);
    int aBase[4], bBase[2];
    #pragma unroll
    for (int mb = 0; mb < 4; ++mb) aBase[mb] = (wm * 128 + mb * 32 + lr32) * 32;
    #pragma unroll
    for (int nb = 0; nb < 2; ++nb) bBase[nb] = (wn * 64 + nb * 32 + lr32) * 32;

#define DSAS(dst, BUF, S) do { _Pragma("unroll")                              \
    for (int mb = 0; mb < 4; ++mb)                                            \
        dst[mb] = *(const bf16x8*)&smem[(BUF)*16384 + ((S)>>1)*8192 +         \
                                        aBase[mb] + (cOff ^ (((S)&1)<<4))]; } while (0)
#define DSBS(dst, BUF, S) do { _Pragma("unroll")                              \
    for (int nb = 0; nb < 2; ++nb)                                            \
        dst[nb] = *(const bf16x8*)&smem[32768 + (BUF)*16384 + ((S)>>1)*8192 + \
                                        bBase[nb] + (cOff ^ (((S)&1)<<4))]; } while (0)

#define LGK(n) do { asm volatile("s_waitcnt lgkmcnt(" #n ")" ::: "memory");   \
                    __builtin_amdgcn_sched_barrier(0); } while (0)
#define CKPT(n) do { asm volatile("s_waitcnt vmcnt(" #n ")" ::: "memory");    \
    __builtin_amdgcn_s_barrier(); __builtin_amdgcn_sched_barrier(0); } while (0)

#define MFM8(A_, B_) do { __builtin_amdgcn_s_setprio(1); _Pragma("unroll")    \
    for (int mb = 0; mb < 4; ++mb) _Pragma("unroll")                          \
        for (int nb = 0; nb < 2; ++nb)                                        \
            acc[mb * 2 + nb] = __builtin_amdgcn_mfma_f32_32x32x16_bf16(       \
                A_[mb], B_[nb], acc[mb * 2 + nb], 0, 0, 0);                   \
    __builtin_amdgcn_s_setprio(0); } while (0)

// Tile t in buffer BUF, staging tile t+1 at k-offset kof into BUF^1.
// Entry: X = slice0 frags of BUF (6 reads in flight).  Exit: X = slice0 of
// next tile (BUF^1), reads in flight.
#define TILE_MAIN(BUF, kof) do {                                              \
    DSAS(aY, BUF, 1);  DSBS(bY, BUF, 1);  STA((BUF)^1, 0, kof);               \
    LGK(6);  MFM8(aX, bX);                                                    \
    CKPT(2);                                                                  \
    DSAS(aX, BUF, 2);  DSBS(bX, BUF, 2);  STB((BUF)^1, 0, kof);               \
    LGK(6);  MFM8(aY, bY);                                                    \
    DSAS(aY, BUF, 3);  DSBS(bY, BUF, 3);  STA((BUF)^1, 1, kof);               \
    LGK(6);  MFM8(aX, bX);                                                    \
    CKPT(2);                                                                  \
    DSAS(aX, (BUF)^1, 0);  DSBS(bX, (BUF)^1, 0);  STB((BUF)^1, 1, kof);       \
    LGK(6);  MFM8(aY, bY);                                                    \
} while (0)

#define TILE_LAST(BUF) do {                                                   \
    DSAS(aY, BUF, 1);  DSBS(bY, BUF, 1);                                      \
    LGK(6);  MFM8(aX, bX);                                                    \
    CKPT(0);                                                                  \
    DSAS(aX, BUF, 2);  DSBS(bX, BUF, 2);                                      \
    LGK(6);  MFM8(aY, bY);                                                    \
    DSAS(aY, BUF, 3);  DSBS(bY, BUF, 3);                                      \
    LGK(6);  MFM8(aX, bX);                                                    \
    LGK(0);  MFM8(aY, bY);                                                    \
} while (0)

    f32x16 acc[8];
    #pragma unroll
    for (int b = 0; b < 8; ++b)
        #pragma unroll
        for (int r = 0; r < 16; ++r) acc[b][r] = 0.0f;

    bf16x8 aX[4], aY[4], bX[2], bY[2];

    // prologue: stage tile 0 halves; wait h0; preload slice-0 fragments.
    STA(0, 0, 0); STB(0, 0, 0); STA(0, 1, 0); STB(0, 1, 0);
    CKPT(4);
    DSAS(aX, 0, 0); DSBS(bX, 0, 0);

    #pragma unroll 1
    for (int t = 0; t + 2 < NT; t += 2) {
        TILE_MAIN(0, (long)(t + 1) * 64);
        TILE_MAIN(1, (long)(t + 2) * 64);
    }
    TILE_MAIN(0, (long)(NT - 1) * 64);
    TILE_LAST(1);

    // epilogue: C/D col = lane&31, row = (reg&3)+8*(reg>>2)+4*(lane>>5)
    const long crow0 = m0 + wm * 128;
    const long ccol0 = n0 + wn * 64;
    u16*   Cb = (u16*)Cout   + (long)bz * sC;
    float* Cf = (float*)Cout + (long)bz * sC;
    const float* resz = res + (long)bz * sR;
    #pragma unroll
    for (int mb = 0; mb < 4; ++mb) {
        #pragma unroll
        for (int nb = 0; nb < 2; ++nb) {
            const long col = ccol0 + nb * 32 + lr32;
            float bv_ = 0.0f;
            if (HAS_BIAS) bv_ = bias[col];
            if (OUT_MODE == 2) {
                #pragma unroll
                for (int rq = 0; rq < 4; ++rq) {
                    const long row0 = crow0 + mb * 32 + rq * 8 + lk2 * 4;
                    u16x4 pk;
                    #pragma unroll
                    for (int r = 0; r < 4; ++r) {
                        float v = acc[mb * 2 + nb][rq * 4 + r] + bv_;
                        v *= scale;
                        pk[r] = f2b(v);
                    }
                    const long b_ = row0 >> 12, s_ = row0 & 4095;
                    *(u16x4*)((u16*)Cout + (b_ << 22) + (col << 12) + s_) = pk;
                }
            } else {
                #pragma unroll
                for (int rq = 0; rq < 4; ++rq) {
                    #pragma unroll
                    for (int r = 0; r < 4; ++r) {
                        const long row = crow0 + mb * 32 + rq * 8 + lk2 * 4 + r;
                        float v = acc[mb * 2 + nb][rq * 4 + r];
                        if (HAS_BIAS) v += bv_;
                        v *= scale;
                        if (RELU) v = fmaxf(v, 0.0f);
                        if (HAS_RES) v += resz[row * (long)N + col];
                        if (OUT_MODE == 1) Cf[row * (long)N + col] = v;
                        else               Cb[row * (long)N + col] = f2b(v);
                    }
                }
            }
        }
    }
#undef STA
#undef STB
#undef DSAS
#undef DSBS
#undef LGK
#undef CKPT
#undef MFM8
#undef TILE_MAIN
#undef TILE_LAST
}

// distinct names per role for rocprof attribution ----------------------------
__global__ __launch_bounds__(512, 2) void g12_proj(
    const u16* A, const u16* Bt, const float* bias, u16* C, int N, int K)
{ gemm12_body<1,0,0,0>(A, Bt, bias, nullptr, C, N, K, 0,0,0,0, 1.0f); }

__global__ __launch_bounds__(512, 2) void g12_vproj(
    const u16* A, const u16* Bt, const float* bias, u16* C, int N, int K)
{ gemm12_body<1,0,0,2>(A, Bt, bias, nullptr, C, N, K, 0,0,0,0, 1.0f); }

__global__ __launch_bounds__(512, 2) void g12_qkt(
    const u16* A, const u16* Bt, u16* C, int N, int K,
    long sA, long sB, long sC, float scale)
{ gemm12_body<0,0,0,0>(A, Bt, nullptr, nullptr, C, N, K, sA, sB, sC, 0, scale); }

__global__ __launch_bounds__(512, 2) void g12_pv(
    const u16* A, const u16* Bt, const float* res, u16* C, int N, int K,
    long sA, long sB, long sC, long sR)
{ gemm12_body<0,0,1,0>(A, Bt, nullptr, res, C, N, K, sA, sB, sC, sR, 1.0f); }

__global__ __launch_bounds__(512, 2) void g12_ffn1(
    const u16* A, const u16* Bt, const float* bias, u16* C, int N, int K)
{ gemm12_body<1,1,0,0>(A, Bt, bias, nullptr, C, N, K, 0,0,0,0, 1.0f); }

__global__ __launch_bounds__(512, 2) void g12_ffn2(
    const u16* A, const u16* Bt, const float* bias, float* C, int N, int K, float scale)
{ gemm12_body<1,0,0,1>(A, Bt, bias, nullptr, C, N, K, 0,0,0,0, scale); }

// ---------------------------------------------------------------------------
__global__ __launch_bounds__(256) void cvt_f32_bf16(
    const float* __restrict__ in, u16* __restrict__ out, long n)
{
    long i = ((long)blockIdx.x * 256 + threadIdx.x) * 4;
    if (i >= n) return;
    float4 f = *(const float4*)(in + i);
    u16x4 o;
    o[0] = f2b(f.x); o[1] = f2b(f.y); o[2] = f2b(f.z); o[3] = f2b(f.w);
    *(u16x4*)(out + i) = o;
}

__global__ __launch_bounds__(256) void transpose_to_bf16(
    const float* __restrict__ in, u16* __restrict__ out, int R, int C)
{
    __shared__ float tile[32][33];
    const int bx = blockIdx.x * 32;
    const int by = blockIdx.y * 32;
    const int tx = threadIdx.x, ty = threadIdx.y;
    #pragma unroll
    for (int i = 0; i < 32; i += 8)
        tile[ty + i][tx] = in[(long)(by + ty + i) * C + bx + tx];
    __syncthreads();
    #pragma unroll
    for (int i = 0; i < 32; i += 8)
        out[(long)(bx + ty + i) * R + by + tx] = f2b(tile[tx][ty + i]);
}

// in-place row softmax over n=4096 bf16 elements; one block per row.
__global__ __launch_bounds__(256) void softmax_rows(u16* __restrict__ P, int n)
{
    const int t = threadIdx.x;
    const int lane = t & 63, w = t >> 6;
    u16* row = P + (long)blockIdx.x * n;
    u16x8 a = *(const u16x8*)(row + t * 16);
    u16x8 b = *(const u16x8*)(row + t * 16 + 8);
    float v[16];
    #pragma unroll
    for (int i = 0; i < 8; ++i) { v[i] = b2f(a[i]); v[8 + i] = b2f(b[i]); }

    float mx = v[0];
    #pragma unroll
    for (int i = 1; i < 16; ++i) mx = fmaxf(mx, v[i]);
    #pragma unroll
    for (int o = 32; o > 0; o >>= 1) mx = fmaxf(mx, __shfl_xor(mx, o));
    __shared__ float red[8];
    if (lane == 0) red[w] = mx;
    __syncthreads();
    mx = fmaxf(fmaxf(red[0], red[1]), fmaxf(red[2], red[3]));

    float s = 0.0f;
    #pragma unroll
    for (int i = 0; i < 16; ++i) { v[i] = __expf(v[i] - mx); s += v[i]; }
    #pragma unroll
    for (int o = 32; o > 0; o >>= 1) s += __shfl_xor(s, o);
    if (lane == 0) red[4 + w] = s;
    __syncthreads();
    s = red[4] + red[5] + red[6] + red[7];
    const float inv = 1.0f / s;

    #pragma unroll
    for (int i = 0; i < 8; ++i) { a[i] = f2b(v[i] * inv); b[i] = f2b(v[8 + i] * inv); }
    *(u16x8*)(row + t * 16)     = a;
    *(u16x8*)(row + t * 16 + 8) = b;
}

// ---------------------------------------------------------------------------
extern "C" void kernel_launch(void* const* d_in, const int* in_sizes, int n_in,
                              void* d_out, int out_size, void* d_ws, size_t ws_size,
                              hipStream_t stream)
{
    (void)in_sizes; (void)n_in; (void)out_size;
    const float* x  = (const float*)d_in[0];
    const float* Wq = (const float*)d_in[1];
    const float* bq = (const float*)d_in[2];
    const float* Wk = (const float*)d_in[3];
    const float* bk = (const float*)d_in[4];
    const float* Wv = (const float*)d_in[5];
    const float* bv = (const float*)d_in[6];
    const float* W1 = (const float*)d_in[7];
    const float* b1 = (const float*)d_in[8];
    const float* W2 = (const float*)d_in[9];
    const float* b2 = (const float*)d_in[10];
    float* out = (float*)d_out;

    const int  B = 4, S = 4096, D = 1024;
    const long SD  = (long)S * D;           // 4 Mi
    const long BSD = (long)B * SD;          // 16 Mi
    const long SS  = (long)S * S;           // 16 Mi

    // score-chunk size BC: P holds BC*SS elems, aliasing xb (dead after proj)
    int BC = 4;
    while (BC > 1 && (size_t)((long)BC * SS + 5L * D * D + 3L * BSD) * 2 > ws_size)
        BC >>= 1;

    // workspace layout (u16 elements)
    u16* Pb = (u16*)d_ws;            // [BC, S, S] scores; xb aliases Pb
    u16* xb = Pb;                    // [B*S, D] x bf16 (dead after proj)
    u16* Wt = Pb + (long)BC * SS;    // 5 x [D, D]
    u16* Qb = Wt + 5L * D * D;       // [B*S, D]   (later: h)
    u16* Kb = Qb + BSD;              // [B*S, D]   (later: x_res)
    u16* Vt = Kb + BSD;              // B x [D, S]

    cvt_f32_bf16<<<dim3((unsigned)(BSD / 4 / 256)), 256, 0, stream>>>(x, xb, BSD);

    dim3 tb(32, 8);
    transpose_to_bf16<<<dim3(D / 32, D / 32), tb, 0, stream>>>(Wq, Wt + 0L * D * D, D, D);
    transpose_to_bf16<<<dim3(D / 32, D / 32), tb, 0, stream>>>(Wk, Wt + 1L * D * D, D, D);
    transpose_to_bf16<<<dim3(D / 32, D / 32), tb, 0, stream>>>(Wv, Wt + 2L * D * D, D, D);
    transpose_to_bf16<<<dim3(D / 32, D / 32), tb, 0, stream>>>(W1, Wt + 3L * D * D, D, D);
    transpose_to_bf16<<<dim3(D / 32, D / 32), tb, 0, stream>>>(W2, Wt + 4L * D * D, D, D);

    const dim3 gproj(D / 256, (B * S) / 256);    // (4, 64) = 256 blocks
    g12_proj <<<gproj, 512, 0, stream>>>(xb, Wt + 0L*D*D, bq, Qb, D, D);
    g12_proj <<<gproj, 512, 0, stream>>>(xb, Wt + 1L*D*D, bk, Kb, D, D);
    g12_vproj<<<gproj, 512, 0, stream>>>(xb, Wt + 2L*D*D, bv, Vt, D, D);
    // xb is dead from here; Pb may overwrite it.

    for (int c = 0; c < B; c += BC) {
        g12_qkt<<<dim3(S/256, S/256, BC), 512, 0, stream>>>(
            Qb + (long)c * SD, Kb + (long)c * SD, Pb, S, D, SD, SD, SS, 0.03125f);
        softmax_rows<<<BC * S, 256, 0, stream>>>(Pb, S);
        g12_pv<<<dim3(D/256, S/256, BC), 512, 0, stream>>>(
            Pb, Vt + (long)c * SD, x + (long)c * SD, Kb + (long)c * SD,
            D, S, SS, SD, SD, SD);
    }

    // FFN: h = relu(x_res @ W1 + b1) -> Qb;  out = 2*(h @ W2 + b2) fp32
    g12_ffn1<<<gproj, 512, 0, stream>>>(Kb, Wt + 3L*D*D, b1, Qb, D, D);
    g12_ffn2<<<gproj, 512, 0, stream>>>(Qb, Wt + 4L*D*D, b2, out, D, D, 2.0f);
}

// Round 10
// 530.506 us; speedup vs baseline: 1.0109x; 1.0109x over previous
//
#include <hip/hip_runtime.h>
#include <stdint.h>

typedef unsigned short u16;
typedef __bf16 bf16x8 __attribute__((ext_vector_type(8)));
typedef float f32x4 __attribute__((ext_vector_type(4)));
typedef unsigned short u16x8 __attribute__((ext_vector_type(8)));
typedef unsigned short u16x4 __attribute__((ext_vector_type(4)));

__device__ __forceinline__ float b2f(u16 b) {
    return __uint_as_float(((unsigned)b) << 16);
}
__device__ __forceinline__ u16 f2b(float f) {
    unsigned u = __float_as_uint(f);
    unsigned r = (u + 0x7fffu + ((u >> 16) & 1u)) >> 16;  // RNE
    return (u16)r;
}

#define GLDS16(g, l) __builtin_amdgcn_global_load_lds(                        \
    (const __attribute__((address_space(1))) void*)(g),                       \
    (__attribute__((address_space(3))) void*)(l), 16, 0, 0)

#define BAR()  __builtin_amdgcn_s_barrier()
#define LG0()  do { asm volatile("s_waitcnt lgkmcnt(0)" ::: "memory");        \
                    __builtin_amdgcn_sched_barrier(0); } while (0)
#define WVM4() asm volatile("s_waitcnt vmcnt(4)" ::: "memory")
#define WVM0() asm volatile("s_waitcnt vmcnt(0)" ::: "memory")

// ---------------------------------------------------------------------------
// 256x256-tile 8-phase GEMM (m201-style template = r5's g8 schedule) with
// the r8-verified conflict-free chunk-XOR LDS addressing.
// C = epilogue(A @ Bt^T); A[M,K], Bt[N,K] bf16 row-major.  512 thr = 8 waves
// (2M x 4N); per-wave C = 128x64; 16x16x32 MFMA.  BK=64 as 2 K-halves stored
// [256 rows][4 chunks of 8 elems] (64B rows), physical chunk = logical chunk
// ^ ((row>>1)&3) applied BOTH sides (staged via pre-swizzled global source;
// read via lkA = lk ^ ((lr>>1)&3)) -- counter-verified 0 conflicts in r8.
// Phase structure per K-tile t (4 phases; m201: ds-reads + 1 stage before
// barrier, lgkmcnt(0) after barrier, bare 16-MFMA cluster, second barrier;
// counted vmcnt once per K-tile at phases 1 and 3, never 0 in steady state):
//   P0: LDA(kh0)+LDB(kh0,nh0) | STA(nxt,kh0) | BAR lgkm0 MFMA_Q(0) BAR
//   P1: LDB(kh0,nh1)          | STB(nxt,kh0) | BAR lgkm0 MFMA_Q(1) vm4 BAR
//   P2: LDA(kh1)+LDB(kh1,nh1) | STA(nxt,kh1) | BAR lgkm0 MFMA_Q(1) BAR
//   P3: LDB(kh1,nh0)          | STB(nxt,kh1) | BAR lgkm0 MFMA_Q(0) vm4 BAR
// OUT_MODE: 0 = bf16 [.,N], 1 = f32 [.,N], 2 = bf16 V^T scatter
//           (b = row>>12, Vt[b][col][row&4095], batch stride 1<<22).
// ---------------------------------------------------------------------------
template<int HAS_BIAS, int RELU, int HAS_RES, int OUT_MODE>
__device__ __forceinline__ void gemm13_body(
    const u16* __restrict__ A, const u16* __restrict__ Bt,
    const float* __restrict__ bias, const float* __restrict__ res,
    void* __restrict__ Cout, int N, int K,
    long sA, long sB, long sC, long sR, float scale)
{
    __shared__ u16 smem[65536];   // 128 KiB: A [buf][kh] 16KB x4, then B x4

    // chunked XCD swizzle (bijective; all grids here have nwg % 8 == 0)
    const long nwg = (long)gridDim.x * gridDim.y * gridDim.z;
    long gid = ((long)blockIdx.z * gridDim.y + blockIdx.y) * gridDim.x + blockIdx.x;
    long logical = (nwg % 8 == 0) ? (gid & 7) * (nwg >> 3) + (gid >> 3) : gid;
    const int bx = (int)(logical % gridDim.x);
    long tmp = logical / gridDim.x;
    const int by = (int)(tmp % gridDim.y);
    const int bz = (int)(tmp / gridDim.y);

    A  += (long)bz * sA;
    Bt += (long)bz * sB;

    const int tid  = threadIdx.x;
    const int lane = tid & 63, wid = tid >> 6;
    const int wm   = wid >> 2, wn = wid & 3;
    const int lr   = lane & 15, lk = lane >> 4;
    const long m0  = (long)by * 256;
    const long n0  = (long)bx * 256;
    const int  NT  = K >> 6;

    // staging source with inverse chunk swizzle (r8-verified): thread tid
    // covers LDS slot (row=tid>>2, chunk=tid&3); fetches logical chunk
    // (tid&3)^((tid>>3)&3).
    const int sch = ((tid & 3) ^ ((tid >> 3) & 3)) * 8;
    const u16* gA0 = A  + (m0 + (tid >> 2)) * (long)K + sch;
    const u16* gB0 = Bt + (n0 + (tid >> 2)) * (long)K + sch;
    const u16* gA1 = gA0 + 128L * K;
    const u16* gB1 = gB0 + 128L * K;
    const int wdst = (tid & ~63) * 8;   // u16 elems

#define STA(bufn, kh, kof) do {                                               \
    GLDS16(gA0 + (kof) + (kh) * 32, &smem[(bufn)*16384 + (kh)*8192 + wdst]);  \
    GLDS16(gA1 + (kof) + (kh) * 32, &smem[(bufn)*16384 + (kh)*8192 + wdst + 4096]); } while (0)
#define STB(bufn, kh, kof) do {                                               \
    GLDS16(gB0 + (kof) + (kh) * 32, &smem[32768 + (bufn)*16384 + (kh)*8192 + wdst]); \
    GLDS16(gB1 + (kof) + (kh) * 32, &smem[32768 + (bufn)*16384 + (kh)*8192 + wdst + 4096]); } while (0)

    // fragment reads: chunk swizzled by lkA = lk ^ ((lr>>1)&3) (0-conflict
    // pattern, r8); per-frag row offsets are multiples of 16 rows -> f(row)
    // invariant.
    const int lkA    = lk ^ ((lr >> 1) & 3);
    const int raBase = (wm * 128 + lr) * 32 + lkA * 8;   // + i*512 per frag
    const int rbBase = (wn * 64  + lr) * 32 + lkA * 8;   // + nh*1024 + jj*512

#define LDA(c, kh) do { _Pragma("unroll")                                     \
    for (int i = 0; i < 8; ++i)                                               \
        a[i] = *(const bf16x8*)&smem[(c)*16384 + (kh)*8192 + raBase + i*512]; } while (0)
#define LDB(c, kh, nh) do { _Pragma("unroll")                                 \
    for (int jj = 0; jj < 2; ++jj)                                            \
        b[jj] = *(const bf16x8*)&smem[32768 + (c)*16384 + (kh)*8192 + rbBase + (nh)*1024 + jj*512]; } while (0)

#define MFMA_Q(nh) do { __builtin_amdgcn_s_setprio(1); _Pragma("unroll")      \
    for (int i = 0; i < 8; ++i) _Pragma("unroll")                             \
        for (int jj = 0; jj < 2; ++jj)                                        \
            acc[i][(nh)*2 + jj] = __builtin_amdgcn_mfma_f32_16x16x32_bf16(    \
                a[i], b[jj], acc[i][(nh)*2 + jj], 0, 0, 0);                   \
    __builtin_amdgcn_s_setprio(0); } while (0)

    f32x4 acc[8][4];
    #pragma unroll
    for (int i = 0; i < 8; ++i)
        #pragma unroll
        for (int j = 0; j < 4; ++j)
            #pragma unroll
            for (int r = 0; r < 4; ++r) acc[i][j][r] = 0.0f;

    // prologue: stage K-tile 0 (h0=A-k0, h1=B-k0, h2=A-k1, h3=B-k1)
    STA(0, 0, 0); STB(0, 0, 0); STA(0, 1, 0); STB(0, 1, 0);
    WVM4();           // h0,h1 landed (h2,h3 still in flight)
    BAR();

    #pragma unroll 1
    for (int t = 0; t < NT; ++t) {
        const int cur = t & 1, nxt = cur ^ 1;
        const long kN = (long)(t + 1) * 64;
        const bool st = (t + 1 < NT);
        bf16x8 a[8], b[2];

        // phase 0: (kh0, nh0)
        LDA(cur, 0); LDB(cur, 0, 0);
        if (st) STA(nxt, 0, kN);
        BAR(); LG0();
        MFMA_Q(0);
        BAR();
        // phase 1: (kh0, nh1)
        LDB(cur, 0, 1);
        if (st) STB(nxt, 0, kN);
        BAR(); LG0();
        MFMA_Q(1);
        if (st) { WVM4(); } else { WVM0(); }   // current tile h2,h3 landed
        BAR();
        // phase 2: (kh1, nh1)
        LDA(cur, 1); LDB(cur, 1, 1);
        if (st) STA(nxt, 1, kN);
        BAR(); LG0();
        MFMA_Q(1);
        BAR();
        // phase 3: (kh1, nh0)
        LDB(cur, 1, 0);
        if (st) STB(nxt, 1, kN);
        BAR(); LG0();
        MFMA_Q(0);
        if (st) { WVM4(); } else { WVM0(); }   // next tile h0,h1 landed
        BAR();
    }

    // epilogue: C/D layout col = lane&15, row = (lane>>4)*4 + reg  [m89]
    const long crow0 = m0 + wm * 128;
    const long ccol0 = n0 + wn * 64;
    u16*   Cb = (u16*)Cout   + (long)bz * sC;
    float* Cf = (float*)Cout + (long)bz * sC;
    const float* resz = res + (long)bz * sR;
    #pragma unroll
    for (int i = 0; i < 8; ++i) {
        #pragma unroll
        for (int j = 0; j < 4; ++j) {
            const long col = ccol0 + j * 16 + lr;
            float bv_ = 0.0f;
            if (HAS_BIAS) bv_ = bias[col];
            if (OUT_MODE == 2) {
                const long row0 = crow0 + i * 16 + lk * 4;
                u16x4 pk;
                #pragma unroll
                for (int r = 0; r < 4; ++r) {
                    float v = acc[i][j][r] + bv_;
                    v *= scale;
                    pk[r] = f2b(v);
                }
                const long b_ = row0 >> 12, s_ = row0 & 4095;
                *(u16x4*)((u16*)Cout + (b_ << 22) + (col << 12) + s_) = pk;
            } else {
                #pragma unroll
                for (int r = 0; r < 4; ++r) {
                    const long row = crow0 + i * 16 + lk * 4 + r;
                    float v = acc[i][j][r];
                    if (HAS_BIAS) v += bv_;
                    v *= scale;
                    if (RELU) v = fmaxf(v, 0.0f);
                    if (HAS_RES) v += resz[row * (long)N + col];
                    if (OUT_MODE == 1) Cf[row * (long)N + col] = v;
                    else               Cb[row * (long)N + col] = f2b(v);
                }
            }
        }
    }
#undef STA
#undef STB
#undef LDA
#undef LDB
#undef MFMA_Q
}

// distinct names per role for rocprof attribution ----------------------------
__global__ __launch_bounds__(512, 2) void g13_proj(
    const u16* A, const u16* Bt, const float* bias, u16* C, int N, int K)
{ gemm13_body<1,0,0,0>(A, Bt, bias, nullptr, C, N, K, 0,0,0,0, 1.0f); }

__global__ __launch_bounds__(512, 2) void g13_vproj(
    const u16* A, const u16* Bt, const float* bias, u16* C, int N, int K)
{ gemm13_body<1,0,0,2>(A, Bt, bias, nullptr, C, N, K, 0,0,0,0, 1.0f); }

__global__ __launch_bounds__(512, 2) void g13_qkt(
    const u16* A, const u16* Bt, u16* C, int N, int K,
    long sA, long sB, long sC, float scale)
{ gemm13_body<0,0,0,0>(A, Bt, nullptr, nullptr, C, N, K, sA, sB, sC, 0, scale); }

__global__ __launch_bounds__(512, 2) void g13_pv(
    const u16* A, const u16* Bt, const float* res, u16* C, int N, int K,
    long sA, long sB, long sC, long sR)
{ gemm13_body<0,0,1,0>(A, Bt, nullptr, res, C, N, K, sA, sB, sC, sR, 1.0f); }

__global__ __launch_bounds__(512, 2) void g13_ffn1(
    const u16* A, const u16* Bt, const float* bias, u16* C, int N, int K)
{ gemm13_body<1,1,0,0>(A, Bt, bias, nullptr, C, N, K, 0,0,0,0, 1.0f); }

__global__ __launch_bounds__(512, 2) void g13_ffn2(
    const u16* A, const u16* Bt, const float* bias, float* C, int N, int K, float scale)
{ gemm13_body<1,0,0,1>(A, Bt, bias, nullptr, C, N, K, 0,0,0,0, scale); }

// ---------------------------------------------------------------------------
__global__ __launch_bounds__(256) void cvt_f32_bf16(
    const float* __restrict__ in, u16* __restrict__ out, long n)
{
    long i = ((long)blockIdx.x * 256 + threadIdx.x) * 4;
    if (i >= n) return;
    float4 f = *(const float4*)(in + i);
    u16x4 o;
    o[0] = f2b(f.x); o[1] = f2b(f.y); o[2] = f2b(f.z); o[3] = f2b(f.w);
    *(u16x4*)(out + i) = o;
}

__global__ __launch_bounds__(256) void transpose_to_bf16(
    const float* __restrict__ in, u16* __restrict__ out, int R, int C)
{
    __shared__ float tile[32][33];
    const int bx = blockIdx.x * 32;
    const int by = blockIdx.y * 32;
    const int tx = threadIdx.x, ty = threadIdx.y;
    #pragma unroll
    for (int i = 0; i < 32; i += 8)
        tile[ty + i][tx] = in[(long)(by + ty + i) * C + bx + tx];
    __syncthreads();
    #pragma unroll
    for (int i = 0; i < 32; i += 8)
        out[(long)(bx + ty + i) * R + by + tx] = f2b(tile[tx][ty + i]);
}

// in-place row softmax over n=4096 bf16 elements; one block per row.
__global__ __launch_bounds__(256) void softmax_rows(u16* __restrict__ P, int n)
{
    const int t = threadIdx.x;
    const int lane = t & 63, w = t >> 6;
    u16* row = P + (long)blockIdx.x * n;
    u16x8 a = *(const u16x8*)(row + t * 16);
    u16x8 b = *(const u16x8*)(row + t * 16 + 8);
    float v[16];
    #pragma unroll
    for (int i = 0; i < 8; ++i) { v[i] = b2f(a[i]); v[8 + i] = b2f(b[i]); }

    float mx = v[0];
    #pragma unroll
    for (int i = 1; i < 16; ++i) mx = fmaxf(mx, v[i]);
    #pragma unroll
    for (int o = 32; o > 0; o >>= 1) mx = fmaxf(mx, __shfl_xor(mx, o));
    __shared__ float red[8];
    if (lane == 0) red[w] = mx;
    __syncthreads();
    mx = fmaxf(fmaxf(red[0], red[1]), fmaxf(red[2], red[3]));

    float s = 0.0f;
    #pragma unroll
    for (int i = 0; i < 16; ++i) { v[i] = __expf(v[i] - mx); s += v[i]; }
    #pragma unroll
    for (int o = 32; o > 0; o >>= 1) s += __shfl_xor(s, o);
    if (lane == 0) red[4 + w] = s;
    __syncthreads();
    s = red[4] + red[5] + red[6] + red[7];
    const float inv = 1.0f / s;

    #pragma unroll
    for (int i = 0; i < 8; ++i) { a[i] = f2b(v[i] * inv); b[i] = f2b(v[8 + i] * inv); }
    *(u16x8*)(row + t * 16)     = a;
    *(u16x8*)(row + t * 16 + 8) = b;
}

// ---------------------------------------------------------------------------
extern "C" void kernel_launch(void* const* d_in, const int* in_sizes, int n_in,
                              void* d_out, int out_size, void* d_ws, size_t ws_size,
                              hipStream_t stream)
{
    (void)in_sizes; (void)n_in; (void)out_size;
    const float* x  = (const float*)d_in[0];
    const float* Wq = (const float*)d_in[1];
    const float* bq = (const float*)d_in[2];
    const float* Wk = (const float*)d_in[3];
    const float* bk = (const float*)d_in[4];
    const float* Wv = (const float*)d_in[5];
    const float* bv = (const float*)d_in[6];
    const float* W1 = (const float*)d_in[7];
    const float* b1 = (const float*)d_in[8];
    const float* W2 = (const float*)d_in[9];
    const float* b2 = (const float*)d_in[10];
    float* out = (float*)d_out;

    const int  B = 4, S = 4096, D = 1024;
    const long SD  = (long)S * D;           // 4 Mi
    const long BSD = (long)B * SD;          // 16 Mi
    const long SS  = (long)S * S;           // 16 Mi

    // score-chunk size BC: P holds BC*SS elems, aliasing xb (dead after proj)
    int BC = 4;
    while (BC > 1 && (size_t)((long)BC * SS + 5L * D * D + 3L * BSD) * 2 > ws_size)
        BC >>= 1;

    // workspace layout (u16 elements)
    u16* Pb = (u16*)d_ws;            // [BC, S, S] scores; xb aliases Pb
    u16* xb = Pb;                    // [B*S, D] x bf16 (dead after proj)
    u16* Wt = Pb + (long)BC * SS;    // 5 x [D, D]
    u16* Qb = Wt + 5L * D * D;       // [B*S, D]   (later: h)
    u16* Kb = Qb + BSD;              // [B*S, D]   (later: x_res)
    u16* Vt = Kb + BSD;              // B x [D, S]

    cvt_f32_bf16<<<dim3((unsigned)(BSD / 4 / 256)), 256, 0, stream>>>(x, xb, BSD);

    dim3 tb(32, 8);
    transpose_to_bf16<<<dim3(D / 32, D / 32), tb, 0, stream>>>(Wq, Wt + 0L * D * D, D, D);
    transpose_to_bf16<<<dim3(D / 32, D / 32), tb, 0, stream>>>(Wk, Wt + 1L * D * D, D, D);
    transpose_to_bf16<<<dim3(D / 32, D / 32), tb, 0, stream>>>(Wv, Wt + 2L * D * D, D, D);
    transpose_to_bf16<<<dim3(D / 32, D / 32), tb, 0, stream>>>(W1, Wt + 3L * D * D, D, D);
    transpose_to_bf16<<<dim3(D / 32, D / 32), tb, 0, stream>>>(W2, Wt + 4L * D * D, D, D);

    const dim3 gproj(D / 256, (B * S) / 256);    // (4, 64) = 256 blocks
    g13_proj <<<gproj, 512, 0, stream>>>(xb, Wt + 0L*D*D, bq, Qb, D, D);
    g13_proj <<<gproj, 512, 0, stream>>>(xb, Wt + 1L*D*D, bk, Kb, D, D);
    g13_vproj<<<gproj, 512, 0, stream>>>(xb, Wt + 2L*D*D, bv, Vt, D, D);
    // xb is dead from here; Pb may overwrite it.

    for (int c = 0; c < B; c += BC) {
        g13_qkt<<<dim3(S/256, S/256, BC), 512, 0, stream>>>(
            Qb + (long)c * SD, Kb + (long)c * SD, Pb, S, D, SD, SD, SS, 0.03125f);
        softmax_rows<<<BC * S, 256, 0, stream>>>(Pb, S);
        g13_pv<<<dim3(D/256, S/256, BC), 512, 0, stream>>>(
            Pb, Vt + (long)c * SD, x + (long)c * SD, Kb + (long)c * SD,
            D, S, SS, SD, SD, SD);
    }

    // FFN: h = relu(x_res @ W1 + b1) -> Qb;  out = 2*(h @ W2 + b2) fp32
    g13_ffn1<<<gproj, 512, 0, stream>>>(Kb, Wt + 3L*D*D, b1, Qb, D, D);
    g13_ffn2<<<gproj, 512, 0, stream>>>(Qb, Wt + 4L*D*D, b2, out, D, D, 2.0f);
}